// Round 4
// baseline (87.254 us; speedup 1.0000x reference)
//
#include <hip/hip_runtime.h>
#include <hip/hip_fp16.h>
#include <math.h>

#define C 64
#define IN_DIM 148
#define ODIM 9      // outputs per edge
#define PROW 9      // halfs per proj row (18 B packed -> sp+dp = 3.6 MB, fits per-XCD L2)

typedef _Float16 half_t;
typedef float f4 __attribute__((ext_vector_type(4)));   // clang-native vector (nontemporal-ok)

__device__ __forceinline__ float tanh_fast(float x) {
    // tanh(x) = 1 - 2/(e^{2x}+1); saturates correctly at +/-inf
    float e = __expf(2.0f * x);
    return 1.0f - 2.0f / (e + 1.0f);
}

// ---------------- node projection kernel: 1 thread per (node, src/dst half) --
__global__ __launch_bounds__(256) void node_proj_kernel(
    const float* __restrict__ x, const int* __restrict__ node_types,
    const float* __restrict__ W, half_t* __restrict__ sp, half_t* __restrict__ dp,
    int N)
{
    __shared__ float Wl[2 * ODIM][C];   // r<9: W[r][c]; r>=9: W[r-9][64+c]
    __shared__ float ntab[2][ODIM][4];  // [0]=src-type consts, [1]=dst-type consts

    for (int i = threadIdx.x; i < 2 * ODIM * C; i += 256) {
        int r = i >> 6, c = i & 63;
        int o = (r < ODIM) ? r : r - ODIM;
        int col = (r < ODIM) ? c : (C + c);
        Wl[r][c] = W[o * IN_DIM + col];
    }
    for (int i = threadIdx.x; i < 2 * ODIM * 4; i += 256) {
        int t = i & 3;
        int o = (i >> 2) % ODIM;
        int sd = (i >> 2) / ODIM;
        ntab[sd][o][t] = W[o * IN_DIM + 128 + sd * 4 + t];
    }
    __syncthreads();

    int tid = blockIdx.x * 256 + threadIdx.x;
    int n = tid >> 1;
    int h = tid & 1;                    // 0 = src-proj, 1 = dst-proj
    if (n >= N) return;

    const f4* xr = (const f4*)(x + (size_t)n * C);

    float acc[ODIM];
#pragma unroll
    for (int o = 0; o < ODIM; ++o) acc[o] = 0.0f;

#pragma unroll
    for (int q = 0; q < 16; ++q) {
        f4 xv = __builtin_nontemporal_load(xr + q);  // paired lanes share the line
#pragma unroll
        for (int o = 0; o < ODIM; ++o) {
            f4 w = *(const f4*)&Wl[h * ODIM + o][q * 4];
            acc[o] = fmaf(xv.x, w.x, acc[o]);
            acc[o] = fmaf(xv.y, w.y, acc[o]);
            acc[o] = fmaf(xv.z, w.z, acc[o]);
            acc[o] = fmaf(xv.w, w.w, acc[o]);
        }
    }

    int t = node_types[n];
    half_t* r = (h ? dp : sp) + (size_t)n * PROW;
#pragma unroll
    for (int o = 0; o < ODIM; ++o)
        r[o] = (half_t)(acc[o] + ntab[h][o][t]);
}

// ---------------- edge kernel: one thread per output element ----------------
__global__ __launch_bounds__(256) void edge_kernel(
    const int* __restrict__ ei, const int* __restrict__ etypes,
    const half_t* __restrict__ sp, const half_t* __restrict__ dp,
    const float* __restrict__ W, float* __restrict__ out,
    int E)
{
    __shared__ float etab[12 * ODIM];   // etab[t*9+o] = W[o][136+t]
    for (int i = threadIdx.x; i < 12 * ODIM; i += 256) {
        int t = i / ODIM, o = i - t * ODIM;
        etab[i] = W[o * IN_DIM + 136 + t];
    }
    __syncthreads();

    int i = blockIdx.x * 256 + threadIdx.x;
    int total = E * ODIM;               // 14.4M fits int32
    if (i >= total) return;

    unsigned e = (unsigned)i / 9u;      // magic-mul division
    int o = i - (int)e * 9;

    // streaming data: non-temporal so it doesn't evict the proj gather set from L2
    int s  = __builtin_nontemporal_load(ei + e);
    int d  = __builtin_nontemporal_load(ei + (size_t)E + e);
    int et = __builtin_nontemporal_load(etypes + e);

    float v = (float)sp[(size_t)s * PROW + o]
            + (float)dp[(size_t)d * PROW + o]
            + etab[et * ODIM + o];
    __builtin_nontemporal_store(tanh_fast(v), out + i);
}

extern "C" void kernel_launch(void* const* d_in, const int* in_sizes, int n_in,
                              void* d_out, int out_size, void* d_ws, size_t ws_size,
                              hipStream_t stream) {
    const float* x      = (const float*)d_in[0];
    const int*   ei     = (const int*)d_in[1];
    const int*   etypes = (const int*)d_in[2];
    const int*   ntypes = (const int*)d_in[3];
    const float* W      = (const float*)d_in[4];
    float* out = (float*)d_out;

    int N = in_sizes[0] / C;    // 100000
    int E = in_sizes[2];        // 1600000

    half_t* sp = (half_t*)d_ws;
    half_t* dp = sp + (size_t)N * PROW;

    int nthreads = N * 2;
    int nblocks  = (nthreads + 255) / 256;
    node_proj_kernel<<<nblocks, 256, 0, stream>>>(x, ntypes, W, sp, dp, N);

    long total = (long)E * ODIM;
    int eblocks = (int)((total + 255) / 256);
    edge_kernel<<<eblocks, 256, 0, stream>>>(ei, etypes, sp, dp, W, out, E);
}

// Round 5
// 54.491 us; speedup vs baseline: 1.6012x; 1.6012x over previous
//
#include <hip/hip_runtime.h>
#include <math.h>

#define C 64
#define IN_DIM 148
#define ODIM 9      // outputs per edge
#define PROW 10     // halfs per proj row (20 B, 4B-aligned rows; sp+dp = 4.0 MB, L2-resident)

typedef _Float16 half_t;
typedef float f4 __attribute__((ext_vector_type(4)));
typedef f4 f4u __attribute__((aligned(4)));           // 4B-aligned 16B vector
typedef _Float16 h8 __attribute__((ext_vector_type(8)));
typedef h8 h8u __attribute__((aligned(4)));
typedef _Float16 h2 __attribute__((ext_vector_type(2)));

__device__ __forceinline__ float tanh_fast(float x) {
    // tanh(x) = 1 - 2/(e^{2x}+1); saturates correctly at +/-inf
    float e = __expf(2.0f * x);
    return 1.0f - 2.0f / (e + 1.0f);
}

// ---------------- node projection kernel: 1 thread per node ----------------
__global__ __launch_bounds__(256) void node_proj_kernel(
    const float* __restrict__ x, const int* __restrict__ node_types,
    const float* __restrict__ W, half_t* __restrict__ sp, half_t* __restrict__ dp,
    int N)
{
    __shared__ float Wl[2 * ODIM][C];   // r<9: W[r][c]; r>=9: W[r-9][64+c]
    __shared__ float ntab[2][ODIM][4];  // [0]=src-type consts, [1]=dst-type consts

    for (int i = threadIdx.x; i < 2 * ODIM * C; i += 256) {
        int r = i >> 6, c = i & 63;
        int o = (r < ODIM) ? r : r - ODIM;
        int col = (r < ODIM) ? c : (C + c);
        Wl[r][c] = W[o * IN_DIM + col];
    }
    for (int i = threadIdx.x; i < 2 * ODIM * 4; i += 256) {
        int t = i & 3;
        int o = (i >> 2) % ODIM;
        int sd = (i >> 2) / ODIM;
        ntab[sd][o][t] = W[o * IN_DIM + 128 + sd * 4 + t];
    }
    __syncthreads();

    int n = blockIdx.x * 256 + threadIdx.x;
    if (n >= N) return;

    f4 xv[16];                           // whole x-row in registers (cached loads)
    const f4* xr = (const f4*)(x + (size_t)n * C);
#pragma unroll
    for (int q = 0; q < 16; ++q) xv[q] = xr[q];

    float acc[2 * ODIM];
#pragma unroll
    for (int o = 0; o < 2 * ODIM; ++o) acc[o] = 0.0f;

#pragma unroll
    for (int q = 0; q < 16; ++q) {
#pragma unroll
        for (int o = 0; o < 2 * ODIM; ++o) {
            f4 w = *(const f4*)&Wl[o][q * 4];   // broadcast ds_read_b128
            acc[o] = fmaf(xv[q].x, w.x, acc[o]);
            acc[o] = fmaf(xv[q].y, w.y, acc[o]);
            acc[o] = fmaf(xv[q].z, w.z, acc[o]);
            acc[o] = fmaf(xv[q].w, w.w, acc[o]);
        }
    }

    int t = node_types[n];
    half_t srow[PROW], drow[PROW];
#pragma unroll
    for (int o = 0; o < ODIM; ++o) {
        srow[o] = (half_t)(acc[o] + ntab[0][o][t]);
        drow[o] = (half_t)(acc[ODIM + o] + ntab[1][o][t]);
    }
    srow[9] = (half_t)0.0f;
    drow[9] = (half_t)0.0f;

    half_t* srp = sp + (size_t)n * PROW;
    half_t* drp = dp + (size_t)n * PROW;
    *(h8u*)srp = *(h8*)srow;             // 16B store (4B-aligned ok)
    *(h2*)(srp + 8) = *(h2*)(srow + 8);  // 4B store
    *(h8u*)drp = *(h8*)drow;
    *(h2*)(drp + 8) = *(h2*)(drow + 8);
}

// ---------------- edge kernel: ONE THREAD PER EDGE ----------------
__global__ __launch_bounds__(256) void edge_kernel(
    const int* __restrict__ ei, const int* __restrict__ etypes,
    const half_t* __restrict__ sp, const half_t* __restrict__ dp,
    const float* __restrict__ W, float* __restrict__ out,
    int E)
{
    __shared__ float etab[12][ODIM];    // etab[t][o] = W[o][136+t]
    for (int i = threadIdx.x; i < 12 * ODIM; i += 256) {
        int t = i / ODIM, o = i - t * ODIM;
        etab[t][o] = W[o * IN_DIM + 136 + t];
    }
    __syncthreads();

    int e = blockIdx.x * 256 + threadIdx.x;
    if (e >= E) return;

    // streaming: non-temporal so it doesn't evict the L2-resident proj set
    int s  = __builtin_nontemporal_load(ei + e);
    int d  = __builtin_nontemporal_load(ei + (size_t)E + e);
    int et = __builtin_nontemporal_load(etypes + e);

    // two 20B row gathers, 2 loads each, all independent -> 7 loads in flight
    const half_t* srp = sp + (size_t)s * PROW;
    const half_t* drp = dp + (size_t)d * PROW;
    h8 sv  = *(const h8u*)srp;
    h2 sv2 = *(const h2*)(srp + 8);
    h8 dv  = *(const h8u*)drp;
    h2 dv2 = *(const h2*)(drp + 8);

    const float* eb = &etab[et][0];

    float r[ODIM];
#pragma unroll
    for (int o = 0; o < 8; ++o)
        r[o] = (float)sv[o] + (float)dv[o] + eb[o];
    r[8] = (float)sv2[0] + (float)dv2[0] + eb[8];

#pragma unroll
    for (int o = 0; o < ODIM; ++o) r[o] = tanh_fast(r[o]);

    float* op = out + (size_t)e * ODIM;  // 36B contiguous per thread
    f4 v0 = {r[0], r[1], r[2], r[3]};
    f4 v1 = {r[4], r[5], r[6], r[7]};
    __builtin_nontemporal_store(v0, (f4u*)op);
    __builtin_nontemporal_store(v1, (f4u*)(op + 4));
    __builtin_nontemporal_store(r[8], op + 8);
}

extern "C" void kernel_launch(void* const* d_in, const int* in_sizes, int n_in,
                              void* d_out, int out_size, void* d_ws, size_t ws_size,
                              hipStream_t stream) {
    const float* x      = (const float*)d_in[0];
    const int*   ei     = (const int*)d_in[1];
    const int*   etypes = (const int*)d_in[2];
    const int*   ntypes = (const int*)d_in[3];
    const float* W      = (const float*)d_in[4];
    float* out = (float*)d_out;

    int N = in_sizes[0] / C;    // 100000
    int E = in_sizes[2];        // 1600000

    half_t* sp = (half_t*)d_ws;
    half_t* dp = sp + (size_t)N * PROW;

    int nblocks = (N + 255) / 256;
    node_proj_kernel<<<nblocks, 256, 0, stream>>>(x, ntypes, W, sp, dp, N);

    int eblocks = (E + 255) / 256;
    edge_kernel<<<eblocks, 256, 0, stream>>>(ei, etypes, sp, dp, W, out, E);
}